// Round 1
// baseline (547.469 us; speedup 1.0000x reference)
//
#include <hip/hip_runtime.h>

#define NN 100000
#define IC 128
#define HD 64
#define NEG 0.2f

// out <- bias broadcast; denom <- 0
__global__ __launch_bounds__(256) void k_init(float* __restrict__ out,
                                              const float* __restrict__ bias,
                                              float* __restrict__ denom) {
  int i = blockIdx.x * 256 + threadIdx.x;
  if (i < NN * HD) out[i] = bias[i & (HD - 1)];
  if (i < NN) denom[i] = 0.f;
}

// h = x @ W  (64-node x 64-ch tile per block), plus a_src = h.att_src, a_dst = h.att_dst
__global__ __launch_bounds__(256) void k_gemm(const float* __restrict__ x,
                                              const float* __restrict__ W,
                                              const float* __restrict__ att_s,
                                              const float* __restrict__ att_d,
                                              float* __restrict__ h,
                                              float* __restrict__ as_,
                                              float* __restrict__ ad_) {
  // xs[k][r ^ sw(k)] : transposed x tile, XOR-swizzled (sw multiple of 4 keeps
  // float4 reads contiguous+aligned; spreads the transpose store across banks)
  __shared__ float xs[IC][64];
  __shared__ float wsm[IC][HD];
  const int tid = threadIdx.x;
  const int n0 = blockIdx.x * 64;

  // load W tile: 128x64 f32, coalesced float4
  #pragma unroll
  for (int i = 0; i < 8; ++i) {
    int f = i * 256 + tid;
    int k = f >> 4, c = (f & 15) << 2;
    *(float4*)&wsm[k][c] = *(const float4*)&W[k * HD + c];
  }
  // load x tile (64 rows x 128), store transposed+swizzled
  #pragma unroll
  for (int i = 0; i < 8; ++i) {
    int f = i * 256 + tid;
    int r = f >> 5, k0 = (f & 31) << 2;
    float4 v = make_float4(0.f, 0.f, 0.f, 0.f);
    if (n0 + r < NN) v = *(const float4*)&x[(size_t)(n0 + r) * IC + k0];
    const float* vf = (const float*)&v;
    #pragma unroll
    for (int j = 0; j < 4; ++j) {
      int k = k0 + j;
      int sw = ((k >> 2) & 7) << 2;
      xs[k][r ^ sw] = vf[j];
    }
  }
  __syncthreads();

  const int c0 = (tid & 15) << 2;   // 16 col-groups
  const int r0 = (tid >> 4) << 2;   // 16 row-groups
  float acc[4][4] = {};
  #pragma unroll 4
  for (int k = 0; k < IC; ++k) {
    int sw = ((k >> 2) & 7) << 2;
    float4 xv = *(float4*)&xs[k][r0 ^ sw];
    float4 wv = *(float4*)&wsm[k][c0];
    float xa[4] = {xv.x, xv.y, xv.z, xv.w};
    float wa[4] = {wv.x, wv.y, wv.z, wv.w};
    #pragma unroll
    for (int a = 0; a < 4; ++a)
      #pragma unroll
      for (int b = 0; b < 4; ++b) acc[a][b] += xa[a] * wa[b];
  }

  float as4[4], ad4[4];
  #pragma unroll
  for (int j = 0; j < 4; ++j) { as4[j] = att_s[c0 + j]; ad4[j] = att_d[c0 + j]; }

  #pragma unroll
  for (int a = 0; a < 4; ++a) {
    int n = n0 + r0 + a;
    float ps = acc[a][0]*as4[0] + acc[a][1]*as4[1] + acc[a][2]*as4[2] + acc[a][3]*as4[3];
    float pd = acc[a][0]*ad4[0] + acc[a][1]*ad4[1] + acc[a][2]*ad4[2] + acc[a][3]*ad4[3];
    // reduce across the 16 lanes (lane&15 varies) holding this row's col-groups
    #pragma unroll
    for (int mk = 1; mk < 16; mk <<= 1) {
      ps += __shfl_xor(ps, mk);
      pd += __shfl_xor(pd, mk);
    }
    if (n < NN) {
      *(float4*)&h[(size_t)n * HD + c0] =
          make_float4(acc[a][0], acc[a][1], acc[a][2], acc[a][3]);
      if ((tid & 15) == 0) { as_[n] = ps; ad_[n] = pd; }
    }
  }
}

// per-edge: p = exp(leaky_relu(a_src[s]+a_dst[d])); denom[d] += p
// (max-subtraction dropped: logits bounded ~13, exp safe in f32; ratios identical)
__global__ __launch_bounds__(256) void k_edge(const int* __restrict__ ei,
                                              const float* __restrict__ as_,
                                              const float* __restrict__ ad_,
                                              float* __restrict__ p,
                                              float* __restrict__ denom,
                                              int E, int M) {
  int m = blockIdx.x * 256 + threadIdx.x;
  if (m >= M) return;
  int s, d;
  if (m < E) { s = ei[m]; d = ei[E + m]; }
  else       { s = m - E; d = s; }           // self-loops appended after edges
  float e = as_[s] + ad_[d];
  e = e > 0.f ? e : NEG * e;
  float pe = __expf(e);
  p[m] = pe;
  atomicAdd(&denom[d], pe);
}

// one wave per edge: alpha = p/denom; out[d] += alpha * h[s]  (lane = channel)
__global__ __launch_bounds__(256) void k_scatter(const int* __restrict__ ei,
                                                 const float* __restrict__ p,
                                                 const float* __restrict__ denom,
                                                 const float* __restrict__ h,
                                                 float* __restrict__ out,
                                                 float* __restrict__ alpha_out,
                                                 int E, int M) {
  int wid = (blockIdx.x * 256 + (int)threadIdx.x) >> 6;
  int lane = threadIdx.x & 63;
  if (wid >= M) return;
  int s, d;
  if (wid < E) { s = ei[wid]; d = ei[E + wid]; }
  else         { s = wid - E; d = s; }
  float alpha = p[wid] / (denom[d] + 1e-16f);
  if (lane == 0) alpha_out[wid] = alpha;
  atomicAdd(&out[(size_t)d * HD + lane], alpha * h[(size_t)s * HD + lane]);
}

extern "C" void kernel_launch(void* const* d_in, const int* in_sizes, int n_in,
                              void* d_out, int out_size, void* d_ws, size_t ws_size,
                              hipStream_t stream) {
  const float* x     = (const float*)d_in[0];
  const int*   ei    = (const int*)d_in[1];   // [2, E]: src row then dst row
  const float* W     = (const float*)d_in[2];
  const float* att_s = (const float*)d_in[3];
  const float* att_d = (const float*)d_in[4];
  const float* bias  = (const float*)d_in[5];

  const int E = in_sizes[1] / 2;
  const int M = E + NN;

  float* out       = (float*)d_out;               // [NN*HD]
  float* alpha_out = out + (size_t)NN * HD;       // [M]

  float* ws    = (float*)d_ws;
  float* h     = ws;                               // NN*HD
  float* as_   = ws + (size_t)NN * HD;             // NN
  float* ad_   = as_ + NN;                         // NN
  float* denom = ad_ + NN;                         // NN
  float* p     = denom + NN;                       // M

  k_init<<<(NN * HD + 255) / 256, 256, 0, stream>>>(out, bias, denom);
  k_gemm<<<(NN + 63) / 64, 256, 0, stream>>>(x, W, att_s, att_d, h, as_, ad_);
  k_edge<<<(M + 255) / 256, 256, 0, stream>>>(ei, as_, ad_, p, denom, E, M);
  k_scatter<<<(M * 64 + 255) / 256, 256, 0, stream>>>(ei, p, denom, h, out,
                                                      alpha_out, E, M);
}

// Round 2
// 395.090 us; speedup vs baseline: 1.3857x; 1.3857x over previous
//
#include <hip/hip_runtime.h>

#define NN 100000
#define IC 128
#define HD 64
#define NEG 0.2f
#define NB_SCAN ((NN + 511) / 512)   // 196 scan blocks

// denom <- 0, degree <- 1 (self-loop), base[NN] <- M
__global__ __launch_bounds__(256) void k_init(float* __restrict__ denom,
                                              int* __restrict__ degree,
                                              int* __restrict__ base, int M) {
  int i = blockIdx.x * 256 + threadIdx.x;
  if (i < NN) { denom[i] = 0.f; degree[i] = 1; }
  if (i == 0) base[NN] = M;
}

// h = x @ W  (64-node x 64-ch tile per block), plus a_src = h.att_src, a_dst = h.att_dst
__global__ __launch_bounds__(256) void k_gemm(const float* __restrict__ x,
                                              const float* __restrict__ W,
                                              const float* __restrict__ att_s,
                                              const float* __restrict__ att_d,
                                              float* __restrict__ h,
                                              float* __restrict__ as_,
                                              float* __restrict__ ad_) {
  __shared__ float xs[IC][64];
  __shared__ float wsm[IC][HD];
  const int tid = threadIdx.x;
  const int n0 = blockIdx.x * 64;

  #pragma unroll
  for (int i = 0; i < 8; ++i) {
    int f = i * 256 + tid;
    int k = f >> 4, c = (f & 15) << 2;
    *(float4*)&wsm[k][c] = *(const float4*)&W[k * HD + c];
  }
  #pragma unroll
  for (int i = 0; i < 8; ++i) {
    int f = i * 256 + tid;
    int r = f >> 5, k0 = (f & 31) << 2;
    float4 v = make_float4(0.f, 0.f, 0.f, 0.f);
    if (n0 + r < NN) v = *(const float4*)&x[(size_t)(n0 + r) * IC + k0];
    const float* vf = (const float*)&v;
    #pragma unroll
    for (int j = 0; j < 4; ++j) {
      int k = k0 + j;
      int sw = ((k >> 2) & 7) << 2;
      xs[k][r ^ sw] = vf[j];
    }
  }
  __syncthreads();

  const int c0 = (tid & 15) << 2;
  const int r0 = (tid >> 4) << 2;
  float acc[4][4] = {};
  #pragma unroll 4
  for (int k = 0; k < IC; ++k) {
    int sw = ((k >> 2) & 7) << 2;
    float4 xv = *(float4*)&xs[k][r0 ^ sw];
    float4 wv = *(float4*)&wsm[k][c0];
    float xa[4] = {xv.x, xv.y, xv.z, xv.w};
    float wa[4] = {wv.x, wv.y, wv.z, wv.w};
    #pragma unroll
    for (int a = 0; a < 4; ++a)
      #pragma unroll
      for (int b = 0; b < 4; ++b) acc[a][b] += xa[a] * wa[b];
  }

  float as4[4], ad4[4];
  #pragma unroll
  for (int j = 0; j < 4; ++j) { as4[j] = att_s[c0 + j]; ad4[j] = att_d[c0 + j]; }

  #pragma unroll
  for (int a = 0; a < 4; ++a) {
    int n = n0 + r0 + a;
    float ps = acc[a][0]*as4[0] + acc[a][1]*as4[1] + acc[a][2]*as4[2] + acc[a][3]*as4[3];
    float pd = acc[a][0]*ad4[0] + acc[a][1]*ad4[1] + acc[a][2]*ad4[2] + acc[a][3]*ad4[3];
    #pragma unroll
    for (int mk = 1; mk < 16; mk <<= 1) {
      ps += __shfl_xor(ps, mk);
      pd += __shfl_xor(pd, mk);
    }
    if (n < NN) {
      *(float4*)&h[(size_t)n * HD + c0] =
          make_float4(acc[a][0], acc[a][1], acc[a][2], acc[a][3]);
      if ((tid & 15) == 0) { as_[n] = ps; ad_[n] = pd; }
    }
  }
}

// degree[dst] += 1 per real edge (self-loops pre-counted via init=1)
__global__ __launch_bounds__(256) void k_count(const int* __restrict__ ei,
                                               int* __restrict__ degree, int E) {
  int m = blockIdx.x * 256 + threadIdx.x;
  if (m < E) atomicAdd(&degree[ei[E + m]], 1);
}

// block-level exclusive scan: 512 elements per block
__global__ __launch_bounds__(256) void k_scanA(const int* __restrict__ deg,
                                               int* __restrict__ base,
                                               int* __restrict__ bsum) {
  int tid = threadIdx.x, blk = blockIdx.x;
  int i0 = blk * 512 + tid * 2;
  int a = (i0 < NN) ? deg[i0] : 0;
  int b = (i0 + 1 < NN) ? deg[i0 + 1] : 0;
  int s = a + b;
  int lane = tid & 63, w = tid >> 6;
  int v = s;
  #pragma unroll
  for (int off = 1; off < 64; off <<= 1) {
    int n = __shfl_up(v, off);
    if (lane >= off) v += n;
  }
  __shared__ int wsum[4];
  if (lane == 63) wsum[w] = v;
  __syncthreads();
  int woff = 0;
  for (int j = 0; j < w; ++j) woff += wsum[j];
  int inc = v + woff;
  int exc = inc - s;
  if (i0 < NN) base[i0] = exc;
  if (i0 + 1 < NN) base[i0 + 1] = exc + a;
  if (tid == 255) bsum[blk] = inc;
}

// scan the 196 block sums (single block)
__global__ __launch_bounds__(256) void k_scanB(const int* __restrict__ bsum,
                                               int* __restrict__ boff) {
  int tid = threadIdx.x;
  int s = (tid < NB_SCAN) ? bsum[tid] : 0;
  int lane = tid & 63, w = tid >> 6;
  int v = s;
  #pragma unroll
  for (int off = 1; off < 64; off <<= 1) {
    int n = __shfl_up(v, off);
    if (lane >= off) v += n;
  }
  __shared__ int wsum[4];
  if (lane == 63) wsum[w] = v;
  __syncthreads();
  int woff = 0;
  for (int j = 0; j < w; ++j) woff += wsum[j];
  if (tid < NB_SCAN) boff[tid] = v + woff - s;
}

// add block offsets; cursor <- base
__global__ __launch_bounds__(256) void k_scanC(int* __restrict__ base,
                                               const int* __restrict__ boff,
                                               int* __restrict__ cursor) {
  int tid = threadIdx.x, blk = blockIdx.x;
  int off = boff[blk];
  int i0 = blk * 512 + tid * 2;
  if (i0 < NN)     { int t = base[i0] + off;     base[i0] = t;     cursor[i0] = t; }
  if (i0 + 1 < NN) { int t = base[i0 + 1] + off; base[i0 + 1] = t; cursor[i0 + 1] = t; }
}

// per-edge: p = exp(leaky_relu(...)); bucket (src,p) by dst; denom[dst] += p
__global__ __launch_bounds__(256) void k_fill(const int* __restrict__ ei,
                                              const float* __restrict__ as_,
                                              const float* __restrict__ ad_,
                                              int* __restrict__ cursor,
                                              int* __restrict__ src_arr,
                                              float* __restrict__ p_arr,
                                              float* __restrict__ denom,
                                              int E, int M) {
  int m = blockIdx.x * 256 + threadIdx.x;
  if (m >= M) return;
  int s, d;
  if (m < E) { s = ei[m]; d = ei[E + m]; }
  else       { s = m - E; d = s; }
  float e = as_[s] + ad_[d];
  e = e > 0.f ? e : NEG * e;
  float pe = __expf(e);
  int slot = atomicAdd(&cursor[d], 1);
  src_arr[slot] = s;
  p_arr[slot] = pe;
  atomicAdd(&denom[d], pe);
}

// one wave per node: out[d] = (sum p*h[src]) / denom + bias   (lane = channel)
__global__ __launch_bounds__(256) void k_gather(const int* __restrict__ base,
                                                const int* __restrict__ src_arr,
                                                const float* __restrict__ p_arr,
                                                const float* __restrict__ denom,
                                                const float* __restrict__ h,
                                                const float* __restrict__ bias,
                                                float* __restrict__ out) {
  int wid = (blockIdx.x * 256 + (int)threadIdx.x) >> 6;
  int lane = threadIdx.x & 63;
  if (wid >= NN) return;
  int beg = base[wid], end = base[wid + 1];
  float acc = 0.f;
  int e = beg;
  for (; e + 1 < end; e += 2) {
    int s0 = src_arr[e], s1 = src_arr[e + 1];
    float p0 = p_arr[e], p1 = p_arr[e + 1];
    acc += p0 * h[(size_t)s0 * HD + lane];
    acc += p1 * h[(size_t)s1 * HD + lane];
  }
  if (e < end) acc += p_arr[e] * h[(size_t)src_arr[e] * HD + lane];
  float rd = 1.f / (denom[wid] + 1e-16f);
  out[(size_t)wid * HD + lane] = acc * rd + bias[lane];
}

// alpha_out[m] = exp(lrelu(as[s]+ad[d])) / denom[d]  (sequential writes)
__global__ __launch_bounds__(256) void k_alpha(const int* __restrict__ ei,
                                               const float* __restrict__ as_,
                                               const float* __restrict__ ad_,
                                               const float* __restrict__ denom,
                                               float* __restrict__ alpha_out,
                                               int E, int M) {
  int m = blockIdx.x * 256 + threadIdx.x;
  if (m >= M) return;
  int s, d;
  if (m < E) { s = ei[m]; d = ei[E + m]; }
  else       { s = m - E; d = s; }
  float e = as_[s] + ad_[d];
  e = e > 0.f ? e : NEG * e;
  alpha_out[m] = __expf(e) / (denom[d] + 1e-16f);
}

extern "C" void kernel_launch(void* const* d_in, const int* in_sizes, int n_in,
                              void* d_out, int out_size, void* d_ws, size_t ws_size,
                              hipStream_t stream) {
  const float* x     = (const float*)d_in[0];
  const int*   ei    = (const int*)d_in[1];   // [2, E]: src row then dst row
  const float* W     = (const float*)d_in[2];
  const float* att_s = (const float*)d_in[3];
  const float* att_d = (const float*)d_in[4];
  const float* bias  = (const float*)d_in[5];

  const int E = in_sizes[1] / 2;
  const int M = E + NN;

  float* out       = (float*)d_out;              // [NN*HD]
  float* alpha_out = out + (size_t)NN * HD;      // [M]

  char* w = (char*)d_ws;
  float* h      = (float*)w;                w += sizeof(float) * (size_t)NN * HD;
  float* as_    = (float*)w;                w += sizeof(float) * NN;
  float* ad_    = (float*)w;                w += sizeof(float) * NN;
  float* denom  = (float*)w;                w += sizeof(float) * NN;
  int*   degree = (int*)w;                  w += sizeof(int) * NN;
  int*   base   = (int*)w;                  w += sizeof(int) * (NN + 1);
  int*   cursor = (int*)w;                  w += sizeof(int) * NN;
  int*   bsum   = (int*)w;                  w += sizeof(int) * 256;
  int*   boff   = (int*)w;                  w += sizeof(int) * 256;
  int*   src_arr= (int*)w;                  w += sizeof(int) * (size_t)M;
  float* p_arr  = (float*)w;                w += sizeof(float) * (size_t)M;

  k_init<<<(NN + 255) / 256, 256, 0, stream>>>(denom, degree, base, M);
  k_gemm<<<(NN + 63) / 64, 256, 0, stream>>>(x, W, att_s, att_d, h, as_, ad_);
  k_count<<<(E + 255) / 256, 256, 0, stream>>>(ei, degree, E);
  k_scanA<<<NB_SCAN, 256, 0, stream>>>(degree, base, bsum);
  k_scanB<<<1, 256, 0, stream>>>(bsum, boff);
  k_scanC<<<NB_SCAN, 256, 0, stream>>>(base, boff, cursor);
  k_fill<<<(M + 255) / 256, 256, 0, stream>>>(ei, as_, ad_, cursor, src_arr,
                                              p_arr, denom, E, M);
  k_gather<<<((size_t)NN * 64 + 255) / 256, 256, 0, stream>>>(
      base, src_arr, p_arr, denom, h, bias, out);
  k_alpha<<<(M + 255) / 256, 256, 0, stream>>>(ei, as_, ad_, denom, alpha_out,
                                               E, M);
}